// Round 1
// baseline (17262.914 us; speedup 1.0000x reference)
//
#include <hip/hip_runtime.h>
#include <cstdint>
#include <cstddef>

// ---------------- problem constants ----------------
namespace {
constexpr int Bb = 8, Ss = 2048, Ee = 256, Hh = 256, G4 = 1024, Tt = 12;
constexpr int NTOK = Bb * Ss;              // 16384 rows
constexpr int NC = 256, LCH = 64;          // viterbi chunking: 256 chunks x 64 steps
constexpr float FNEG = -10000.0f;
constexpr int START_TAG = 10, STOP_TAG = 11;

// ---------------- workspace layout (bytes) ----------------
constexpr size_t OFF_XS    = 0;                         // [16384][256] f32 gathered embeddings
constexpr size_t SZ_XS     = (size_t)NTOK * Ee * 4;
constexpr size_t OFF_WT    = OFF_XS + SZ_XS;            // [2][256][1024] f32 w_ih transposed
constexpr size_t SZ_WT     = (size_t)2 * Ee * G4 * 4;
constexpr size_t OFF_XPF   = OFF_WT + SZ_WT;            // [2048][8][1024] f32 x-proj fwd (bias folded)
constexpr size_t SZ_XP     = (size_t)Ss * Bb * G4 * 4;
constexpr size_t OFF_XPB   = OFF_XPF + SZ_XP;
constexpr size_t OFF_HF    = OFF_XPB + SZ_XP;           // [2048][8][256] f32 fwd hidden history
constexpr size_t SZ_H      = (size_t)Ss * Bb * Hh * 4;
constexpr size_t OFF_HB    = OFF_HF + SZ_H;
constexpr size_t OFF_FEATS = OFF_HB + SZ_H;             // [16384][12] f32
constexpr size_t SZ_FEATS  = (size_t)NTOK * Tt * 4;
constexpr size_t OFF_PMAT  = OFF_FEATS + SZ_FEATS;      // [256][144] f32 chunk max-plus mats
constexpr size_t SZ_PMAT   = (size_t)NC * 144 * 4;
constexpr size_t OFF_FVIN  = OFF_PMAT + SZ_PMAT;        // [256][12] f32 chunk-entry fv
constexpr size_t SZ_FVIN   = (size_t)NC * Tt * 4;
constexpr size_t OFF_BPTR  = OFF_FVIN + SZ_FVIN;        // [16384] u64 packed 12x4bit backptrs
constexpr size_t SZ_BPTR   = (size_t)NTOK * 8;
constexpr size_t OFF_CMAP  = OFF_BPTR + SZ_BPTR;        // [256][12] int chunk composed maps
constexpr size_t SZ_CMAP   = (size_t)NC * Tt * 4;
constexpr size_t OFF_EVEC  = OFF_CMAP + SZ_CMAP;        // [256] int tag at chunk-end
constexpr size_t SZ_EVEC   = (size_t)NC * 4;
constexpr size_t OFF_BEST  = OFF_EVEC + SZ_EVEC;        // [1] int
constexpr size_t SZ_BEST   = 256;
constexpr size_t OFF_HCUR  = OFF_BEST + SZ_BEST;        // [2 dir][2 par][2048] f32 (layout [k][b])
constexpr size_t SZ_HCUR   = 65536;
constexpr size_t OFF_FLAGS = OFF_HCUR + SZ_HCUR;        // [2 dir][8] int
constexpr size_t SZ_FLAGS  = 256;
constexpr size_t WS_NEED   = OFF_FLAGS + SZ_FLAGS;      // ~179 MB

__device__ __forceinline__ float4 f4fma(float a, float4 b, float4 c) {
  c.x = fmaf(a, b.x, c.x); c.y = fmaf(a, b.y, c.y);
  c.z = fmaf(a, b.z, c.z); c.w = fmaf(a, b.w, c.w);
  return c;
}
}  // namespace

// ---------------- init: zero sync flags ----------------
__global__ void k_init(int* flags) {
  if (threadIdx.x < 64) flags[threadIdx.x] = 0;
}

// ---------------- gather embeddings: xs[r=t*8+b][k] = emb[sentence[b][t]][k] ----------------
__global__ __launch_bounds__(256) void k_gather(const int* __restrict__ sent,
                                                const float* __restrict__ emb,
                                                float* __restrict__ xs) {
  int rr = threadIdx.x >> 3, p = threadIdx.x & 7;
  int r = blockIdx.x * 32 + rr;
  int tg = r >> 3, bg = r & 7;
  int tok = sent[bg * Ss + tg];
  const float4* src = (const float4*)(emb + (size_t)tok * Ee) + p * 8;
  float4* dst = (float4*)(xs + (size_t)r * Ee) + p * 8;
#pragma unroll
  for (int i = 0; i < 8; ++i) dst[i] = src[i];
}

// ---------------- transpose w_ih -> wT[d][k][n] ----------------
__global__ __launch_bounds__(256) void k_transpose(const float* __restrict__ w_f,
                                                   const float* __restrict__ w_b,
                                                   float* __restrict__ wT) {
  int idx = blockIdx.x * 256 + threadIdx.x;
  if (idx >= 2 * Ee * G4) return;
  int d = idx >> 18;
  int rem = idx & 262143;
  int k = rem >> 10, n = rem & 1023;
  const float* w = d ? w_b : w_f;
  wT[idx] = w[n * Ee + k];
}

// ---------------- input projection GEMM: xp[r][n] = xs[r][:] . w_ih[n][:] + bias[n] ----------------
__global__ __launch_bounds__(256) void k_inproj(const float* __restrict__ xs,
                                                const float* __restrict__ wT,
                                                const float* __restrict__ b_f,
                                                const float* __restrict__ b_b,
                                                float* __restrict__ xpf,
                                                float* __restrict__ xpb) {
  const int dir = blockIdx.z;
  const float* wTd = wT + (size_t)dir * (Ee * G4);
  const float* bv = dir ? b_b : b_f;
  float* xp = dir ? xpb : xpf;
  const int rg = threadIdx.x >> 5, cg = threadIdx.x & 31;
  const int rbase = blockIdx.x * 32 + rg * 4;
  const int c0 = blockIdx.y * 128 + cg * 4;
  const float4* ap0 = (const float4*)(xs + (size_t)(rbase + 0) * Ee);
  const float4* ap1 = (const float4*)(xs + (size_t)(rbase + 1) * Ee);
  const float4* ap2 = (const float4*)(xs + (size_t)(rbase + 2) * Ee);
  const float4* ap3 = (const float4*)(xs + (size_t)(rbase + 3) * Ee);
  float4 acc0 = {0,0,0,0}, acc1 = {0,0,0,0}, acc2 = {0,0,0,0}, acc3 = {0,0,0,0};
#pragma unroll 4
  for (int k4 = 0; k4 < 64; ++k4) {
    float4 a0 = ap0[k4], a1 = ap1[k4], a2 = ap2[k4], a3 = ap3[k4];
    const float* wb = wTd + (size_t)(k4 * 4) * G4 + c0;
    float4 b0 = *(const float4*)(wb);
    float4 b1 = *(const float4*)(wb + G4);
    float4 b2 = *(const float4*)(wb + 2 * G4);
    float4 b3 = *(const float4*)(wb + 3 * G4);
    acc0 = f4fma(a0.x, b0, acc0); acc0 = f4fma(a0.y, b1, acc0);
    acc0 = f4fma(a0.z, b2, acc0); acc0 = f4fma(a0.w, b3, acc0);
    acc1 = f4fma(a1.x, b0, acc1); acc1 = f4fma(a1.y, b1, acc1);
    acc1 = f4fma(a1.z, b2, acc1); acc1 = f4fma(a1.w, b3, acc1);
    acc2 = f4fma(a2.x, b0, acc2); acc2 = f4fma(a2.y, b1, acc2);
    acc2 = f4fma(a2.z, b2, acc2); acc2 = f4fma(a2.w, b3, acc2);
    acc3 = f4fma(a3.x, b0, acc3); acc3 = f4fma(a3.y, b1, acc3);
    acc3 = f4fma(a3.z, b2, acc3); acc3 = f4fma(a3.w, b3, acc3);
  }
  float4 bias = *(const float4*)(bv + c0);
  acc0.x += bias.x; acc0.y += bias.y; acc0.z += bias.z; acc0.w += bias.w;
  acc1.x += bias.x; acc1.y += bias.y; acc1.z += bias.z; acc1.w += bias.w;
  acc2.x += bias.x; acc2.y += bias.y; acc2.z += bias.z; acc2.w += bias.w;
  acc3.x += bias.x; acc3.y += bias.y; acc3.z += bias.z; acc3.w += bias.w;
  *(float4*)(xp + (size_t)(rbase + 0) * G4 + c0) = acc0;
  *(float4*)(xp + (size_t)(rbase + 1) * G4 + c0) = acc1;
  *(float4*)(xp + (size_t)(rbase + 2) * G4 + c0) = acc2;
  *(float4*)(xp + (size_t)(rbase + 3) * G4 + c0) = acc3;
}

// ---------------- persistent bidirectional LSTM recurrence ----------------
// 16 blocks: wg 0..7 forward, 8..15 backward. Each WG owns 32 hidden channels
// (=128 gate rows), w_hh slice lives in VGPRs. Per-step all-to-all h exchange
// via global hcur (double-buffered) + device-scope flags.
__global__ __launch_bounds__(512, 2) void k_lstm(
    const float* __restrict__ whh_f, const float* __restrict__ whh_b,
    const float* __restrict__ h0, const float* __restrict__ c0,
    const float* __restrict__ xpf, const float* __restrict__ xpb,
    float* __restrict__ hist_f, float* __restrict__ hist_b,
    float* hcur, int* flags) {
  __shared__ __align__(16) float h_lds[2048];   // [k][b]
  __shared__ float part[128 * 33];              // [row][ks*8 + b], pad 33
  __shared__ float z_lds[128 * 9];              // [row][b], pad 9
  __shared__ float h_out[256];                  // [jj*8 + b]

  const int wg = blockIdx.x, dir = wg >> 3, j0 = (wg & 7) * 32;
  const int t = threadIdx.x;
  const float* whh = dir ? whh_b : whh_f;
  const float* xp = dir ? xpb : xpf;
  float* hist = dir ? hist_b : hist_f;
  int* myflags = flags + dir * 8;
  float* hc_d = hcur + dir * 4096;

  // FMA-thread mapping: rowg in lanes, (ks,bs) wave-uniform
  const int rowg = t & 63, ks = (t >> 6) & 3, bs = t >> 8;
  const int row0 = rowg * 2, row1 = rowg * 2 + 1;
  const int n0 = ((row0 >> 5) << 8) + j0 + (row0 & 31);
  const int n1 = ((row1 >> 5) << 8) + j0 + (row1 & 31);
  float4 w0r[16], w1r[16];
  {
    const float4* p0 = (const float4*)(whh + (size_t)n0 * Hh + ks * 64);
    const float4* p1 = (const float4*)(whh + (size_t)n1 * Hh + ks * 64);
#pragma unroll
    for (int q = 0; q < 16; ++q) { w0r[q] = p0[q]; w1r[q] = p1[q]; }
  }
  // reduce-thread z ids (z = row*8 + b, covers 1024 z as t and t+512)
  const int rowA = t >> 3, bA = t & 7;
  const int nA = ((rowA >> 5) << 8) + j0 + (rowA & 31);
  const int rowB = (t + 512) >> 3, bB = t & 7;
  const int nB = ((rowB >> 5) << 8) + j0 + (rowB & 31);
  // gate-thread state
  const int jj = t >> 3, bg = t & 7;
  float c_reg = 0.0f;
  if (t < 256) c_reg = c0[dir * 2048 + bg * Hh + j0 + jj];
  // hist-thread mapping
  const int b2 = t >> 5, jj2 = t & 31;

  for (int s = 0; s < Ss; ++s) {
    const int tg = dir ? (Ss - 1 - s) : s;
    // prefetch x-proj for this step (independent of flags)
    const float xpA = xp[(size_t)tg * 8192 + bA * G4 + nA];
    const float xpB = xp[(size_t)tg * 8192 + bB * G4 + nB];
    if (s > 0 && t < 8) {
      while (__hip_atomic_load(&myflags[t], __ATOMIC_ACQUIRE,
                               __HIP_MEMORY_SCOPE_AGENT) < s) {
        __builtin_amdgcn_s_sleep(1);
      }
    }
    __syncthreads();
    // fill h_lds[k][b]
    if (s == 0) {
#pragma unroll
      for (int i = 0; i < 4; ++i) {
        int idx = t * 4 + i;
        h_lds[idx] = h0[dir * 2048 + (idx & 7) * Hh + (idx >> 3)];
      }
    } else {
      const float4* src = (const float4*)(hc_d + ((s - 1) & 1) * 2048);
      ((float4*)h_lds)[t] = src[t];
    }
    __syncthreads();
    // recurrent GEMM partials: 2 rows x 64 k x 4 b per thread
    float4 accA = {0,0,0,0}, accB = {0,0,0,0};
    const float4* hrow = ((const float4*)h_lds) + ks * 128 + bs;
#pragma unroll
    for (int q = 0; q < 16; ++q) {
      float4 wa = w0r[q], wb = w1r[q];
      float4 hx = hrow[(q * 4 + 0) * 2];
      float4 hy = hrow[(q * 4 + 1) * 2];
      float4 hz = hrow[(q * 4 + 2) * 2];
      float4 hw = hrow[(q * 4 + 3) * 2];
      accA = f4fma(wa.x, hx, accA); accA = f4fma(wa.y, hy, accA);
      accA = f4fma(wa.z, hz, accA); accA = f4fma(wa.w, hw, accA);
      accB = f4fma(wb.x, hx, accB); accB = f4fma(wb.y, hy, accB);
      accB = f4fma(wb.z, hz, accB); accB = f4fma(wb.w, hw, accB);
    }
    {
      int pa = row0 * 33 + ks * 8 + bs * 4;
      part[pa + 0] = accA.x; part[pa + 1] = accA.y;
      part[pa + 2] = accA.z; part[pa + 3] = accA.w;
      int pb = row1 * 33 + ks * 8 + bs * 4;
      part[pb + 0] = accB.x; part[pb + 1] = accB.y;
      part[pb + 2] = accB.z; part[pb + 3] = accB.w;
    }
    __syncthreads();
    // reduce ks-splits + add x-proj(+bias)
    {
      float sA = part[rowA * 33 + bA] + part[rowA * 33 + 8 + bA] +
                 part[rowA * 33 + 16 + bA] + part[rowA * 33 + 24 + bA];
      z_lds[rowA * 9 + bA] = sA + xpA;
      float sB = part[rowB * 33 + bB] + part[rowB * 33 + 8 + bB] +
                 part[rowB * 33 + 16 + bB] + part[rowB * 33 + 24 + bB];
      z_lds[rowB * 9 + bB] = sB + xpB;
    }
    __syncthreads();
    // gates (PyTorch order i,f,g,o)
    if (t < 256) {
      float zi = z_lds[(jj) * 9 + bg];
      float zf = z_lds[(32 + jj) * 9 + bg];
      float zg = z_lds[(64 + jj) * 9 + bg];
      float zo = z_lds[(96 + jj) * 9 + bg];
      float iv = 1.0f / (1.0f + expf(-zi));
      float fv = 1.0f / (1.0f + expf(-zf));
      float gv = tanhf(zg);
      float ov = 1.0f / (1.0f + expf(-zo));
      c_reg = fv * c_reg + iv * gv;
      float hv = ov * tanhf(c_reg);
      hc_d[(s & 1) * 2048 + j0 * 8 + t] = hv;  // [k][b] layout
      h_out[t] = hv;
    }
    __syncthreads();  // hcur stores drained (waitcnt before barrier)
    if (t == 0) {
      __threadfence();  // agent-scope release (L2 writeback on gfx950)
      __hip_atomic_store(&myflags[wg & 7], s + 1, __ATOMIC_RELEASE,
                         __HIP_MEMORY_SCOPE_AGENT);
    }
    if (t < 256) {
      hist[(size_t)tg * 2048 + b2 * Hh + j0 + jj2] = h_out[jj2 * 8 + b2];
    }
  }
}

// ---------------- feats = [hf|hb] @ W_out^T + b_out ----------------
__global__ __launch_bounds__(256) void k_feats(const float* __restrict__ hist_f,
                                               const float* __restrict__ hist_b,
                                               const float* __restrict__ Wout,
                                               const float* __restrict__ bout,
                                               float* __restrict__ feats) {
  __shared__ float wsh[Tt * 512];
  __shared__ float bsh[Tt];
  for (int i = threadIdx.x; i < Tt * 512; i += 256) wsh[i] = Wout[i];
  if (threadIdx.x < Tt) bsh[threadIdx.x] = bout[threadIdx.x];
  __syncthreads();
  int r = blockIdx.x * 256 + threadIdx.x;
  int bq = r >> 11, sq = r & 2047;
  const float4* hf4 = (const float4*)(hist_f + (size_t)sq * 2048 + bq * Hh);
  const float4* hb4 = (const float4*)(hist_b + (size_t)sq * 2048 + bq * Hh);
  float acc[Tt];
#pragma unroll
  for (int j = 0; j < Tt; ++j) acc[j] = bsh[j];
  for (int k4 = 0; k4 < 64; ++k4) {
    float4 x = hf4[k4];
#pragma unroll
    for (int j = 0; j < Tt; ++j) {
      float4 w = *(const float4*)&wsh[j * 512 + k4 * 4];
      acc[j] = fmaf(x.x, w.x, fmaf(x.y, w.y, fmaf(x.z, w.z, fmaf(x.w, w.w, acc[j]))));
    }
  }
  for (int k4 = 0; k4 < 64; ++k4) {
    float4 x = hb4[k4];
#pragma unroll
    for (int j = 0; j < Tt; ++j) {
      float4 w = *(const float4*)&wsh[j * 512 + 256 + k4 * 4];
      acc[j] = fmaf(x.x, w.x, fmaf(x.y, w.y, fmaf(x.z, w.z, fmaf(x.w, w.w, acc[j]))));
    }
  }
#pragma unroll
  for (int j = 0; j < Tt; ++j) feats[(size_t)r * Tt + j] = acc[j];
}

// ---------------- Viterbi phase 1: per-chunk max-plus matrix product ----------------
__global__ __launch_bounds__(192) void k_vit_chunkmat(const float* __restrict__ feats,
                                                      const float* __restrict__ trans,
                                                      float* __restrict__ pmat) {
  __shared__ float R[2][144];
  __shared__ float fe[LCH * Tt];
  __shared__ float ts[144];
  const int t = threadIdx.x, c = blockIdx.x;
  for (int i = t; i < LCH * Tt; i += 192) fe[i] = feats[(size_t)c * LCH * Tt + i];
  if (t < 144) ts[t] = trans[t];
  __syncthreads();
  int j = 0, k = 0;
  float trow[12];
  if (t < 144) {
    j = t / 12; k = t - j * 12;
#pragma unroll
    for (int m = 0; m < 12; ++m) trow[m] = ts[j * 12 + m];
    R[0][t] = ts[t] + fe[j];  // A_{t0}
  }
  __syncthreads();
  for (int i = 1; i < LCH; ++i) {
    int p = (i - 1) & 1;
    if (t < 144) {
      float m = trow[0] + R[p][k];
#pragma unroll
      for (int mm = 1; mm < 12; ++mm) m = fmaxf(m, trow[mm] + R[p][mm * 12 + k]);
      R[p ^ 1][t] = m + fe[i * 12 + j];
    }
    __syncthreads();
  }
  if (t < 144) pmat[(size_t)c * 144 + t] = R[(LCH - 1) & 1][t];
}

// ---------------- Viterbi phase 2: sequential scan over chunk matrices ----------------
__global__ __launch_bounds__(192) void k_vit_scan(const float* __restrict__ pmat,
                                                  const float* __restrict__ trans,
                                                  float* __restrict__ fvin,
                                                  float* __restrict__ dout,
                                                  int* __restrict__ best) {
  __shared__ float fv[12];
  __shared__ float sl[144];
  __shared__ float term[12];
  const int t = threadIdx.x;
  const int j = t / 12, k = t - j * 12;
  if (t < 12) fv[t] = (t == START_TAG) ? 0.0f : FNEG;
  float pv = (t < 144) ? pmat[t] : 0.0f;
  __syncthreads();
  for (int c = 0; c < NC; ++c) {
    if (t < 12) fvin[c * 12 + t] = fv[t];
    float pnext = (t < 144 && c + 1 < NC) ? pmat[(size_t)(c + 1) * 144 + t] : 0.0f;
    if (t < 144) sl[t] = pv + fv[k];
    __syncthreads();
    if (t < 12) {
      float m = sl[t * 12];
#pragma unroll
      for (int kk = 1; kk < 12; ++kk) m = fmaxf(m, sl[t * 12 + kk]);
      fv[t] = m;
    }
    __syncthreads();
    pv = pnext;
  }
  if (t < 12) term[t] = fv[t] + trans[STOP_TAG * 12 + t];
  __syncthreads();
  if (t == 0) {
    float m = term[0]; int a = 0;
    for (int q = 1; q < 12; ++q) { if (term[q] > m) { m = term[q]; a = q; } }
    dout[0] = m;
    best[0] = a;
  }
}

// ---------------- Viterbi phase 3: replay chunks -> packed backpointers ----------------
__global__ __launch_bounds__(64) void k_vit_replay(const float* __restrict__ feats,
                                                   const float* __restrict__ trans,
                                                   const float* __restrict__ fvin,
                                                   unsigned long long* __restrict__ bptr) {
  __shared__ float fe[LCH * Tt];
  __shared__ float fv[12];
  __shared__ int bpn[12];
  const int t = threadIdx.x, c = blockIdx.x;
  for (int i = t; i < LCH * Tt; i += 64) fe[i] = feats[(size_t)c * LCH * Tt + i];
  float trow[12];
  if (t < 12) {
#pragma unroll
    for (int m = 0; m < 12; ++m) trow[m] = trans[t * 12 + m];
    fv[t] = fvin[c * 12 + t];
  }
  __syncthreads();
  for (int i = 0; i < LCH; ++i) {
    float nm = 0.0f;
    if (t < 12) {
      float m = fv[0] + trow[0]; int a = 0;
#pragma unroll
      for (int k = 1; k < 12; ++k) {
        float v = fv[k] + trow[k];
        if (v > m) { m = v; a = k; }   // first-max wins, matches jnp.argmax
      }
      nm = m + fe[i * 12 + t];
      bpn[t] = a;
    }
    __syncthreads();
    if (t < 12) fv[t] = nm;
    if (t == 0) {
      unsigned long long bp = 0;
#pragma unroll
      for (int jq = 0; jq < 12; ++jq)
        bp |= (unsigned long long)(unsigned)bpn[jq] << (4 * jq);
      bptr[(size_t)c * LCH + i] = bp;
    }
    __syncthreads();
  }
}

// ---------------- backtrace phase A: compose per-chunk tag maps ----------------
__global__ __launch_bounds__(64) void k_bt_chunk(const unsigned long long* __restrict__ bptr,
                                                 int* __restrict__ cmap) {
  __shared__ unsigned long long bp[LCH];
  const int t = threadIdx.x, c = blockIdx.x;
  if (t < LCH) bp[t] = bptr[(size_t)c * LCH + t];
  __syncthreads();
  if (t < 12) {
    int v = t;
    for (int i = LCH - 1; i >= 0; --i) v = (int)((bp[i] >> (4 * v)) & 15ULL);
    cmap[c * 12 + t] = v;
  }
}

// ---------------- backtrace phase B: scan chunk maps ----------------
__global__ __launch_bounds__(256) void k_bt_scan(const int* __restrict__ cmap,
                                                 const int* __restrict__ best,
                                                 int* __restrict__ evec) {
  __shared__ int cm[NC * 12];
  __shared__ int es[NC];
  const int t = threadIdx.x;
  for (int i = t; i < NC * 12; i += 256) cm[i] = cmap[i];
  __syncthreads();
  if (t == 0) {
    int tag = best[0];
    es[NC - 1] = tag;
    for (int c = NC - 1; c >= 1; --c) { tag = cm[c * 12 + tag]; es[c - 1] = tag; }
  }
  __syncthreads();
  evec[t] = es[t];
}

// ---------------- backtrace phase C: emit path ----------------
__global__ __launch_bounds__(64) void k_bt_replay(const unsigned long long* __restrict__ bptr,
                                                  const int* __restrict__ evec,
                                                  float* __restrict__ dout) {
  __shared__ unsigned long long bp[LCH];
  __shared__ int tgs[LCH];
  const int t = threadIdx.x, c = blockIdx.x;
  if (t < LCH) bp[t] = bptr[(size_t)c * LCH + t];
  __syncthreads();
  if (t == 0) {
    int tag = evec[c];  // tag at global index (c+1)*LCH
    for (int i = LCH - 1; i >= 0; --i) {
      tgs[i] = tag;                              // out[c*LCH+i] = tag_{c*LCH+i+1}
      tag = (int)((bp[i] >> (4 * tag)) & 15ULL);
    }
  }
  __syncthreads();
  dout[1 + c * LCH + t] = (float)tgs[t];
}

// ---------------- launcher ----------------
extern "C" void kernel_launch(void* const* d_in, const int* in_sizes, int n_in,
                              void* d_out, int out_size, void* d_ws, size_t ws_size,
                              hipStream_t stream) {
  const int*   sent = (const int*)d_in[0];
  const float* emb  = (const float*)d_in[1];
  const float* wihf = (const float*)d_in[2];
  const float* whhf = (const float*)d_in[3];
  const float* bf   = (const float*)d_in[4];
  const float* wihb = (const float*)d_in[5];
  const float* whhb = (const float*)d_in[6];
  const float* bb   = (const float*)d_in[7];
  const float* h0   = (const float*)d_in[8];
  const float* c0   = (const float*)d_in[9];
  const float* Wout = (const float*)d_in[10];
  const float* bout = (const float*)d_in[11];
  const float* trans= (const float*)d_in[12];
  float* out = (float*)d_out;
  char* ws = (char*)d_ws;
  if (ws_size < WS_NEED) return;  // workspace too small: bail (visible as wrong output)

  float* xs    = (float*)(ws + OFF_XS);
  float* wT    = (float*)(ws + OFF_WT);
  float* xpf   = (float*)(ws + OFF_XPF);
  float* xpb   = (float*)(ws + OFF_XPB);
  float* hf    = (float*)(ws + OFF_HF);
  float* hb    = (float*)(ws + OFF_HB);
  float* feats = (float*)(ws + OFF_FEATS);
  float* pmat  = (float*)(ws + OFF_PMAT);
  float* fvin  = (float*)(ws + OFF_FVIN);
  unsigned long long* bptr = (unsigned long long*)(ws + OFF_BPTR);
  int*   cmap  = (int*)(ws + OFF_CMAP);
  int*   evec  = (int*)(ws + OFF_EVEC);
  int*   best  = (int*)(ws + OFF_BEST);
  float* hcur  = (float*)(ws + OFF_HCUR);
  int*   flags = (int*)(ws + OFF_FLAGS);

  hipLaunchKernelGGL(k_init, dim3(1), dim3(64), 0, stream, flags);
  hipLaunchKernelGGL(k_gather, dim3(512), dim3(256), 0, stream, sent, emb, xs);
  hipLaunchKernelGGL(k_transpose, dim3(2048), dim3(256), 0, stream, wihf, wihb, wT);
  hipLaunchKernelGGL(k_inproj, dim3(512, 8, 2), dim3(256), 0, stream,
                     xs, wT, bf, bb, xpf, xpb);
  hipLaunchKernelGGL(k_lstm, dim3(16), dim3(512), 0, stream,
                     whhf, whhb, h0, c0, xpf, xpb, hf, hb, hcur, flags);
  hipLaunchKernelGGL(k_feats, dim3(64), dim3(256), 0, stream, hf, hb, Wout, bout, feats);
  hipLaunchKernelGGL(k_vit_chunkmat, dim3(NC), dim3(192), 0, stream, feats, trans, pmat);
  hipLaunchKernelGGL(k_vit_scan, dim3(1), dim3(192), 0, stream, pmat, trans, fvin, out, best);
  hipLaunchKernelGGL(k_vit_replay, dim3(NC), dim3(64), 0, stream, feats, trans, fvin, bptr);
  hipLaunchKernelGGL(k_bt_chunk, dim3(NC), dim3(64), 0, stream, bptr, cmap);
  hipLaunchKernelGGL(k_bt_scan, dim3(1), dim3(256), 0, stream, cmap, best, evec);
  hipLaunchKernelGGL(k_bt_replay, dim3(NC), dim3(64), 0, stream, bptr, evec, out);
}

// Round 2
// 17074.010 us; speedup vs baseline: 1.0111x; 1.0111x over previous
//
#include <hip/hip_runtime.h>
#include <cstdint>
#include <cstddef>

// ---------------- problem constants ----------------
namespace {
constexpr int Bb = 8, Ss = 2048, Ee = 256, Hh = 256, G4 = 1024, Tt = 12;
constexpr int NTOK = Bb * Ss;              // 16384 rows
constexpr int NC = 256, LCH = 64;          // viterbi chunking: 256 chunks x 64 steps
constexpr float FNEG = -10000.0f;
constexpr int START_TAG = 10, STOP_TAG = 11;

// ---------------- workspace layout (bytes) ----------------
constexpr size_t OFF_XS    = 0;                         // [16384][256] f32 gathered embeddings
constexpr size_t SZ_XS     = (size_t)NTOK * Ee * 4;
constexpr size_t OFF_WT    = OFF_XS + SZ_XS;            // [2][256][1024] f32 w_ih transposed
constexpr size_t SZ_WT     = (size_t)2 * Ee * G4 * 4;
constexpr size_t OFF_XPF   = OFF_WT + SZ_WT;            // [2048][8][1024] f32 x-proj fwd (bias folded)
constexpr size_t SZ_XP     = (size_t)Ss * Bb * G4 * 4;
constexpr size_t OFF_XPB   = OFF_XPF + SZ_XP;
constexpr size_t OFF_HF    = OFF_XPB + SZ_XP;           // [2048][8][256] f32 fwd hidden history
constexpr size_t SZ_H      = (size_t)Ss * Bb * Hh * 4;
constexpr size_t OFF_HB    = OFF_HF + SZ_H;
constexpr size_t OFF_FEATS = OFF_HB + SZ_H;             // [16384][12] f32
constexpr size_t SZ_FEATS  = (size_t)NTOK * Tt * 4;
constexpr size_t OFF_PMAT  = OFF_FEATS + SZ_FEATS;      // [256][144] f32 chunk max-plus mats
constexpr size_t SZ_PMAT   = (size_t)NC * 144 * 4;
constexpr size_t OFF_FVIN  = OFF_PMAT + SZ_PMAT;        // [256][12] f32 chunk-entry fv
constexpr size_t SZ_FVIN   = (size_t)NC * Tt * 4;
constexpr size_t OFF_BPTR  = OFF_FVIN + SZ_FVIN;        // [16384] u64 packed 12x4bit backptrs
constexpr size_t SZ_BPTR   = (size_t)NTOK * 8;
constexpr size_t OFF_CMAP  = OFF_BPTR + SZ_BPTR;        // [256][12] int chunk composed maps
constexpr size_t SZ_CMAP   = (size_t)NC * Tt * 4;
constexpr size_t OFF_EVEC  = OFF_CMAP + SZ_CMAP;        // [256] int tag at chunk-end
constexpr size_t SZ_EVEC   = (size_t)NC * 4;
constexpr size_t OFF_BEST  = OFF_EVEC + SZ_EVEC;        // [1] int
constexpr size_t SZ_BEST   = 256;
constexpr size_t OFF_HPK   = OFF_BEST + SZ_BEST;        // [2 dir][2048] u64 tagged h words
constexpr size_t SZ_HPK    = (size_t)2 * 2048 * 8;
constexpr size_t WS_NEED   = OFF_HPK + SZ_HPK;          // ~179 MB

__device__ __forceinline__ float4 f4fma(float a, float4 b, float4 c) {
  c.x = fmaf(a, b.x, c.x); c.y = fmaf(a, b.y, c.y);
  c.z = fmaf(a, b.z, c.z); c.w = fmaf(a, b.w, c.w);
  return c;
}
}  // namespace

// ---------------- gather embeddings: xs[r=t*8+b][k] = emb[sentence[b][t]][k] ----------------
__global__ __launch_bounds__(256) void k_gather(const int* __restrict__ sent,
                                                const float* __restrict__ emb,
                                                float* __restrict__ xs) {
  int rr = threadIdx.x >> 3, p = threadIdx.x & 7;
  int r = blockIdx.x * 32 + rr;
  int tg = r >> 3, bg = r & 7;
  int tok = sent[bg * Ss + tg];
  const float4* src = (const float4*)(emb + (size_t)tok * Ee) + p * 8;
  float4* dst = (float4*)(xs + (size_t)r * Ee) + p * 8;
#pragma unroll
  for (int i = 0; i < 8; ++i) dst[i] = src[i];
}

// ---------------- transpose w_ih -> wT[d][k][n] ----------------
__global__ __launch_bounds__(256) void k_transpose(const float* __restrict__ w_f,
                                                   const float* __restrict__ w_b,
                                                   float* __restrict__ wT) {
  int idx = blockIdx.x * 256 + threadIdx.x;
  if (idx >= 2 * Ee * G4) return;
  int d = idx >> 18;
  int rem = idx & 262143;
  int k = rem >> 10, n = rem & 1023;
  const float* w = d ? w_b : w_f;
  wT[idx] = w[n * Ee + k];
}

// ---------------- input projection GEMM: xp[r][n] = xs[r][:] . w_ih[n][:] + bias[n] ----------------
__global__ __launch_bounds__(256) void k_inproj(const float* __restrict__ xs,
                                                const float* __restrict__ wT,
                                                const float* __restrict__ b_f,
                                                const float* __restrict__ b_b,
                                                float* __restrict__ xpf,
                                                float* __restrict__ xpb) {
  const int dir = blockIdx.z;
  const float* wTd = wT + (size_t)dir * (Ee * G4);
  const float* bv = dir ? b_b : b_f;
  float* xp = dir ? xpb : xpf;
  const int rg = threadIdx.x >> 5, cg = threadIdx.x & 31;
  const int rbase = blockIdx.x * 32 + rg * 4;
  const int c0 = blockIdx.y * 128 + cg * 4;
  const float4* ap0 = (const float4*)(xs + (size_t)(rbase + 0) * Ee);
  const float4* ap1 = (const float4*)(xs + (size_t)(rbase + 1) * Ee);
  const float4* ap2 = (const float4*)(xs + (size_t)(rbase + 2) * Ee);
  const float4* ap3 = (const float4*)(xs + (size_t)(rbase + 3) * Ee);
  float4 acc0 = {0,0,0,0}, acc1 = {0,0,0,0}, acc2 = {0,0,0,0}, acc3 = {0,0,0,0};
#pragma unroll 4
  for (int k4 = 0; k4 < 64; ++k4) {
    float4 a0 = ap0[k4], a1 = ap1[k4], a2 = ap2[k4], a3 = ap3[k4];
    const float* wb = wTd + (size_t)(k4 * 4) * G4 + c0;
    float4 b0 = *(const float4*)(wb);
    float4 b1 = *(const float4*)(wb + G4);
    float4 b2 = *(const float4*)(wb + 2 * G4);
    float4 b3 = *(const float4*)(wb + 3 * G4);
    acc0 = f4fma(a0.x, b0, acc0); acc0 = f4fma(a0.y, b1, acc0);
    acc0 = f4fma(a0.z, b2, acc0); acc0 = f4fma(a0.w, b3, acc0);
    acc1 = f4fma(a1.x, b0, acc1); acc1 = f4fma(a1.y, b1, acc1);
    acc1 = f4fma(a1.z, b2, acc1); acc1 = f4fma(a1.w, b3, acc1);
    acc2 = f4fma(a2.x, b0, acc2); acc2 = f4fma(a2.y, b1, acc2);
    acc2 = f4fma(a2.z, b2, acc2); acc2 = f4fma(a2.w, b3, acc2);
    acc3 = f4fma(a3.x, b0, acc3); acc3 = f4fma(a3.y, b1, acc3);
    acc3 = f4fma(a3.z, b2, acc3); acc3 = f4fma(a3.w, b3, acc3);
  }
  float4 bias = *(const float4*)(bv + c0);
  acc0.x += bias.x; acc0.y += bias.y; acc0.z += bias.z; acc0.w += bias.w;
  acc1.x += bias.x; acc1.y += bias.y; acc1.z += bias.z; acc1.w += bias.w;
  acc2.x += bias.x; acc2.y += bias.y; acc2.z += bias.z; acc2.w += bias.w;
  acc3.x += bias.x; acc3.y += bias.y; acc3.z += bias.z; acc3.w += bias.w;
  *(float4*)(xp + (size_t)(rbase + 0) * G4 + c0) = acc0;
  *(float4*)(xp + (size_t)(rbase + 1) * G4 + c0) = acc1;
  *(float4*)(xp + (size_t)(rbase + 2) * G4 + c0) = acc2;
  *(float4*)(xp + (size_t)(rbase + 3) * G4 + c0) = acc3;
}

// ---------------- persistent bidirectional LSTM recurrence ----------------
// 16 blocks: wg 0..7 forward, 8..15 backward. Each WG owns 32 hidden channels
// (=128 gate rows), w_hh slice lives in VGPRs. Per-step all-to-all h exchange
// via LLC-coherent tagged 64-bit words: word = (step_tag<<32)|float_bits,
// written/read with relaxed agent-scope atomics (no L2 wb/inv on the path).
__global__ __launch_bounds__(512, 2) void k_lstm(
    const float* __restrict__ whh_f, const float* __restrict__ whh_b,
    const float* __restrict__ h0, const float* __restrict__ c0,
    const float* __restrict__ xpf, const float* __restrict__ xpb,
    float* __restrict__ hist_f, float* __restrict__ hist_b,
    unsigned long long* hpack) {
  __shared__ __align__(16) float h_lds[2048];   // [j][b]
  __shared__ float part[128 * 33];              // [row][ks*8 + b], pad 33
  __shared__ float z_lds[128 * 9];              // [row][b], pad 9
  __shared__ float h_out[256];                  // [jj*8 + b]

  const int wg = blockIdx.x, dir = wg >> 3, j0 = (wg & 7) * 32;
  const int t = threadIdx.x;
  const float* whh = dir ? whh_b : whh_f;
  const float* xp = dir ? xpb : xpf;
  float* hist = dir ? hist_b : hist_f;
  unsigned long long* hpk = hpack + dir * 2048;

  // FMA-thread mapping: rowg in lanes, (ks,bs) wave-uniform
  const int rowg = t & 63, ks = (t >> 6) & 3, bs = t >> 8;
  const int row0 = rowg * 2, row1 = rowg * 2 + 1;
  const int n0 = ((row0 >> 5) << 8) + j0 + (row0 & 31);
  const int n1 = ((row1 >> 5) << 8) + j0 + (row1 & 31);
  float4 w0r[16], w1r[16];
  {
    const float4* p0 = (const float4*)(whh + (size_t)n0 * Hh + ks * 64);
    const float4* p1 = (const float4*)(whh + (size_t)n1 * Hh + ks * 64);
#pragma unroll
    for (int q = 0; q < 16; ++q) { w0r[q] = p0[q]; w1r[q] = p1[q]; }
  }
  // reduce-thread z ids (z = row*8 + b, covers 1024 z as t and t+512)
  const int rowA = t >> 3, bA = t & 7;
  const int nA = ((rowA >> 5) << 8) + j0 + (rowA & 31);
  const int rowB = (t + 512) >> 3, bB = t & 7;
  const int nB = ((rowB >> 5) << 8) + j0 + (rowB & 31);
  // gate-thread state
  const int jj = t >> 3, bg = t & 7;
  float c_reg = 0.0f;
  if (t < 256) c_reg = c0[dir * 2048 + bg * Hh + j0 + jj];
  // hist-thread mapping
  const int b2 = t >> 5, jj2 = t & 31;

  for (int s = 0; s < Ss; ++s) {
    const int tg = dir ? (Ss - 1 - s) : s;
    // prefetch x-proj for this step (overlaps the poll below)
    const float xpA = xp[(size_t)tg * 8192 + bA * G4 + nA];
    const float xpB = xp[(size_t)tg * 8192 + bB * G4 + nB];
    // fill h_lds[j][b] with h_{s-1}
    if (s == 0) {
#pragma unroll
      for (int i = 0; i < 4; ++i) {
        int idx = t * 4 + i;
        h_lds[idx] = h0[dir * 2048 + (idx & 7) * Hh + (idx >> 3)];
      }
    } else {
      const unsigned long long tagv = (unsigned long long)s;
      unsigned long long* p = hpk + 4 * t;
      unsigned long long w0, w1, w2, w3;
      for (;;) {
        w0 = __hip_atomic_load(p + 0, __ATOMIC_RELAXED, __HIP_MEMORY_SCOPE_AGENT);
        w1 = __hip_atomic_load(p + 1, __ATOMIC_RELAXED, __HIP_MEMORY_SCOPE_AGENT);
        w2 = __hip_atomic_load(p + 2, __ATOMIC_RELAXED, __HIP_MEMORY_SCOPE_AGENT);
        w3 = __hip_atomic_load(p + 3, __ATOMIC_RELAXED, __HIP_MEMORY_SCOPE_AGENT);
        if (((w0 >> 32) == tagv) & ((w1 >> 32) == tagv) &
            ((w2 >> 32) == tagv) & ((w3 >> 32) == tagv)) break;
        __builtin_amdgcn_s_sleep(1);
      }
      float4 hv4;
      hv4.x = __uint_as_float((unsigned)w0);
      hv4.y = __uint_as_float((unsigned)w1);
      hv4.z = __uint_as_float((unsigned)w2);
      hv4.w = __uint_as_float((unsigned)w3);
      ((float4*)h_lds)[t] = hv4;
    }
    __syncthreads();
    // recurrent GEMM partials: 2 rows x 64 k x 4 b per thread
    float4 accA = {0,0,0,0}, accB = {0,0,0,0};
    const float4* hrow = ((const float4*)h_lds) + ks * 128 + bs;
#pragma unroll
    for (int q = 0; q < 16; ++q) {
      float4 wa = w0r[q], wb = w1r[q];
      float4 hx = hrow[(q * 4 + 0) * 2];
      float4 hy = hrow[(q * 4 + 1) * 2];
      float4 hz = hrow[(q * 4 + 2) * 2];
      float4 hw = hrow[(q * 4 + 3) * 2];
      accA = f4fma(wa.x, hx, accA); accA = f4fma(wa.y, hy, accA);
      accA = f4fma(wa.z, hz, accA); accA = f4fma(wa.w, hw, accA);
      accB = f4fma(wb.x, hx, accB); accB = f4fma(wb.y, hy, accB);
      accB = f4fma(wb.z, hz, accB); accB = f4fma(wb.w, hw, accB);
    }
    {
      int pa = row0 * 33 + ks * 8 + bs * 4;
      part[pa + 0] = accA.x; part[pa + 1] = accA.y;
      part[pa + 2] = accA.z; part[pa + 3] = accA.w;
      int pb = row1 * 33 + ks * 8 + bs * 4;
      part[pb + 0] = accB.x; part[pb + 1] = accB.y;
      part[pb + 2] = accB.z; part[pb + 3] = accB.w;
    }
    __syncthreads();
    // reduce ks-splits + add x-proj(+bias)
    {
      float sA = part[rowA * 33 + bA] + part[rowA * 33 + 8 + bA] +
                 part[rowA * 33 + 16 + bA] + part[rowA * 33 + 24 + bA];
      z_lds[rowA * 9 + bA] = sA + xpA;
      float sB = part[rowB * 33 + bB] + part[rowB * 33 + 8 + bB] +
                 part[rowB * 33 + 16 + bB] + part[rowB * 33 + 24 + bB];
      z_lds[rowB * 9 + bB] = sB + xpB;
    }
    __syncthreads();
    // gates (PyTorch order i,f,g,o)
    if (t < 256) {
      float zi = z_lds[(jj) * 9 + bg];
      float zf = z_lds[(32 + jj) * 9 + bg];
      float zg = z_lds[(64 + jj) * 9 + bg];
      float zo = z_lds[(96 + jj) * 9 + bg];
      float iv = 1.0f / (1.0f + expf(-zi));
      float fv = 1.0f / (1.0f + expf(-zf));
      float gv = tanhf(zg);
      float ov = 1.0f / (1.0f + expf(-zo));
      c_reg = fv * c_reg + iv * gv;
      float hv = ov * tanhf(c_reg);
      // publish FIRST (critical path for all peer WGs)
      unsigned long long wv =
          ((unsigned long long)(unsigned)(s + 1) << 32) |
          (unsigned long long)__float_as_uint(hv);
      __hip_atomic_store(hpk + j0 * 8 + t, wv, __ATOMIC_RELAXED,
                         __HIP_MEMORY_SCOPE_AGENT);
      h_out[t] = hv;
    }
    __syncthreads();  // h_out visible to hist writers
    if (t < 256) {
      hist[(size_t)tg * 2048 + b2 * Hh + j0 + jj2] = h_out[jj2 * 8 + b2];
    }
  }
}

// ---------------- feats = [hf|hb] @ W_out^T + b_out ----------------
__global__ __launch_bounds__(256) void k_feats(const float* __restrict__ hist_f,
                                               const float* __restrict__ hist_b,
                                               const float* __restrict__ Wout,
                                               const float* __restrict__ bout,
                                               float* __restrict__ feats) {
  __shared__ float wsh[Tt * 512];
  __shared__ float bsh[Tt];
  for (int i = threadIdx.x; i < Tt * 512; i += 256) wsh[i] = Wout[i];
  if (threadIdx.x < Tt) bsh[threadIdx.x] = bout[threadIdx.x];
  __syncthreads();
  int r = blockIdx.x * 256 + threadIdx.x;
  int bq = r >> 11, sq = r & 2047;
  const float4* hf4 = (const float4*)(hist_f + (size_t)sq * 2048 + bq * Hh);
  const float4* hb4 = (const float4*)(hist_b + (size_t)sq * 2048 + bq * Hh);
  float acc[Tt];
#pragma unroll
  for (int j = 0; j < Tt; ++j) acc[j] = bsh[j];
  for (int k4 = 0; k4 < 64; ++k4) {
    float4 x = hf4[k4];
#pragma unroll
    for (int j = 0; j < Tt; ++j) {
      float4 w = *(const float4*)&wsh[j * 512 + k4 * 4];
      acc[j] = fmaf(x.x, w.x, fmaf(x.y, w.y, fmaf(x.z, w.z, fmaf(x.w, w.w, acc[j]))));
    }
  }
  for (int k4 = 0; k4 < 64; ++k4) {
    float4 x = hb4[k4];
#pragma unroll
    for (int j = 0; j < Tt; ++j) {
      float4 w = *(const float4*)&wsh[j * 512 + 256 + k4 * 4];
      acc[j] = fmaf(x.x, w.x, fmaf(x.y, w.y, fmaf(x.z, w.z, fmaf(x.w, w.w, acc[j]))));
    }
  }
#pragma unroll
  for (int j = 0; j < Tt; ++j) feats[(size_t)r * Tt + j] = acc[j];
}

// ---------------- Viterbi phase 1: per-chunk max-plus matrix product ----------------
__global__ __launch_bounds__(192) void k_vit_chunkmat(const float* __restrict__ feats,
                                                      const float* __restrict__ trans,
                                                      float* __restrict__ pmat) {
  __shared__ float R[2][144];
  __shared__ float fe[LCH * Tt];
  __shared__ float ts[144];
  const int t = threadIdx.x, c = blockIdx.x;
  for (int i = t; i < LCH * Tt; i += 192) fe[i] = feats[(size_t)c * LCH * Tt + i];
  if (t < 144) ts[t] = trans[t];
  __syncthreads();
  int j = 0, k = 0;
  float trow[12];
  if (t < 144) {
    j = t / 12; k = t - j * 12;
#pragma unroll
    for (int m = 0; m < 12; ++m) trow[m] = ts[j * 12 + m];
    R[0][t] = ts[t] + fe[j];  // A_{t0}
  }
  __syncthreads();
  for (int i = 1; i < LCH; ++i) {
    int p = (i - 1) & 1;
    if (t < 144) {
      float m = trow[0] + R[p][k];
#pragma unroll
      for (int mm = 1; mm < 12; ++mm) m = fmaxf(m, trow[mm] + R[p][mm * 12 + k]);
      R[p ^ 1][t] = m + fe[i * 12 + j];
    }
    __syncthreads();
  }
  if (t < 144) pmat[(size_t)c * 144 + t] = R[(LCH - 1) & 1][t];
}

// ---------------- Viterbi phase 2: sequential scan over chunk matrices ----------------
__global__ __launch_bounds__(192) void k_vit_scan(const float* __restrict__ pmat,
                                                  const float* __restrict__ trans,
                                                  float* __restrict__ fvin,
                                                  float* __restrict__ dout,
                                                  int* __restrict__ best) {
  __shared__ float fv[12];
  __shared__ float sl[144];
  __shared__ float term[12];
  const int t = threadIdx.x;
  const int j = t / 12, k = t - j * 12;
  if (t < 12) fv[t] = (t == START_TAG) ? 0.0f : FNEG;
  float pv = (t < 144) ? pmat[t] : 0.0f;
  __syncthreads();
  for (int c = 0; c < NC; ++c) {
    if (t < 12) fvin[c * 12 + t] = fv[t];
    float pnext = (t < 144 && c + 1 < NC) ? pmat[(size_t)(c + 1) * 144 + t] : 0.0f;
    if (t < 144) sl[t] = pv + fv[k];
    __syncthreads();
    if (t < 12) {
      float m = sl[t * 12];
#pragma unroll
      for (int kk = 1; kk < 12; ++kk) m = fmaxf(m, sl[t * 12 + kk]);
      fv[t] = m;
    }
    __syncthreads();
    pv = pnext;
  }
  if (t < 12) term[t] = fv[t] + trans[STOP_TAG * 12 + t];
  __syncthreads();
  if (t == 0) {
    float m = term[0]; int a = 0;
    for (int q = 1; q < 12; ++q) { if (term[q] > m) { m = term[q]; a = q; } }
    dout[0] = m;
    best[0] = a;
  }
}

// ---------------- Viterbi phase 3: replay chunks -> packed backpointers ----------------
__global__ __launch_bounds__(64) void k_vit_replay(const float* __restrict__ feats,
                                                   const float* __restrict__ trans,
                                                   const float* __restrict__ fvin,
                                                   unsigned long long* __restrict__ bptr) {
  __shared__ float fe[LCH * Tt];
  __shared__ float fv[12];
  __shared__ int bpn[12];
  const int t = threadIdx.x, c = blockIdx.x;
  for (int i = t; i < LCH * Tt; i += 64) fe[i] = feats[(size_t)c * LCH * Tt + i];
  float trow[12];
  if (t < 12) {
#pragma unroll
    for (int m = 0; m < 12; ++m) trow[m] = trans[t * 12 + m];
    fv[t] = fvin[c * 12 + t];
  }
  __syncthreads();
  for (int i = 0; i < LCH; ++i) {
    float nm = 0.0f;
    if (t < 12) {
      float m = fv[0] + trow[0]; int a = 0;
#pragma unroll
      for (int k = 1; k < 12; ++k) {
        float v = fv[k] + trow[k];
        if (v > m) { m = v; a = k; }   // first-max wins, matches jnp.argmax
      }
      nm = m + fe[i * 12 + t];
      bpn[t] = a;
    }
    __syncthreads();
    if (t < 12) fv[t] = nm;
    if (t == 0) {
      unsigned long long bp = 0;
#pragma unroll
      for (int jq = 0; jq < 12; ++jq)
        bp |= (unsigned long long)(unsigned)bpn[jq] << (4 * jq);
      bptr[(size_t)c * LCH + i] = bp;
    }
    __syncthreads();
  }
}

// ---------------- backtrace phase A: compose per-chunk tag maps ----------------
__global__ __launch_bounds__(64) void k_bt_chunk(const unsigned long long* __restrict__ bptr,
                                                 int* __restrict__ cmap) {
  __shared__ unsigned long long bp[LCH];
  const int t = threadIdx.x, c = blockIdx.x;
  if (t < LCH) bp[t] = bptr[(size_t)c * LCH + t];
  __syncthreads();
  if (t < 12) {
    int v = t;
    for (int i = LCH - 1; i >= 0; --i) v = (int)((bp[i] >> (4 * v)) & 15ULL);
    cmap[c * 12 + t] = v;
  }
}

// ---------------- backtrace phase B: scan chunk maps ----------------
__global__ __launch_bounds__(256) void k_bt_scan(const int* __restrict__ cmap,
                                                 const int* __restrict__ best,
                                                 int* __restrict__ evec) {
  __shared__ int cm[NC * 12];
  __shared__ int es[NC];
  const int t = threadIdx.x;
  for (int i = t; i < NC * 12; i += 256) cm[i] = cmap[i];
  __syncthreads();
  if (t == 0) {
    int tag = best[0];
    es[NC - 1] = tag;
    for (int c = NC - 1; c >= 1; --c) { tag = cm[c * 12 + tag]; es[c - 1] = tag; }
  }
  __syncthreads();
  evec[t] = es[t];
}

// ---------------- backtrace phase C: emit path ----------------
__global__ __launch_bounds__(64) void k_bt_replay(const unsigned long long* __restrict__ bptr,
                                                  const int* __restrict__ evec,
                                                  float* __restrict__ dout) {
  __shared__ unsigned long long bp[LCH];
  __shared__ int tgs[LCH];
  const int t = threadIdx.x, c = blockIdx.x;
  if (t < LCH) bp[t] = bptr[(size_t)c * LCH + t];
  __syncthreads();
  if (t == 0) {
    int tag = evec[c];  // tag at global index (c+1)*LCH
    for (int i = LCH - 1; i >= 0; --i) {
      tgs[i] = tag;                              // out[c*LCH+i] = tag_{c*LCH+i+1}
      tag = (int)((bp[i] >> (4 * tag)) & 15ULL);
    }
  }
  __syncthreads();
  dout[1 + c * LCH + t] = (float)tgs[t];
}

// ---------------- launcher ----------------
extern "C" void kernel_launch(void* const* d_in, const int* in_sizes, int n_in,
                              void* d_out, int out_size, void* d_ws, size_t ws_size,
                              hipStream_t stream) {
  const int*   sent = (const int*)d_in[0];
  const float* emb  = (const float*)d_in[1];
  const float* wihf = (const float*)d_in[2];
  const float* whhf = (const float*)d_in[3];
  const float* bf   = (const float*)d_in[4];
  const float* wihb = (const float*)d_in[5];
  const float* whhb = (const float*)d_in[6];
  const float* bb   = (const float*)d_in[7];
  const float* h0   = (const float*)d_in[8];
  const float* c0   = (const float*)d_in[9];
  const float* Wout = (const float*)d_in[10];
  const float* bout = (const float*)d_in[11];
  const float* trans= (const float*)d_in[12];
  float* out = (float*)d_out;
  char* ws = (char*)d_ws;
  if (ws_size < WS_NEED) return;  // workspace too small: bail (visible as wrong output)

  float* xs    = (float*)(ws + OFF_XS);
  float* wT    = (float*)(ws + OFF_WT);
  float* xpf   = (float*)(ws + OFF_XPF);
  float* xpb   = (float*)(ws + OFF_XPB);
  float* hf    = (float*)(ws + OFF_HF);
  float* hb    = (float*)(ws + OFF_HB);
  float* feats = (float*)(ws + OFF_FEATS);
  float* pmat  = (float*)(ws + OFF_PMAT);
  float* fvin  = (float*)(ws + OFF_FVIN);
  unsigned long long* bptr = (unsigned long long*)(ws + OFF_BPTR);
  int*   cmap  = (int*)(ws + OFF_CMAP);
  int*   evec  = (int*)(ws + OFF_EVEC);
  int*   best  = (int*)(ws + OFF_BEST);
  unsigned long long* hpack = (unsigned long long*)(ws + OFF_HPK);

  hipLaunchKernelGGL(k_gather, dim3(512), dim3(256), 0, stream, sent, emb, xs);
  hipLaunchKernelGGL(k_transpose, dim3(2048), dim3(256), 0, stream, wihf, wihb, wT);
  hipLaunchKernelGGL(k_inproj, dim3(512, 8, 2), dim3(256), 0, stream,
                     xs, wT, bf, bb, xpf, xpb);
  hipLaunchKernelGGL(k_lstm, dim3(16), dim3(512), 0, stream,
                     whhf, whhb, h0, c0, xpf, xpb, hf, hb, hpack);
  hipLaunchKernelGGL(k_feats, dim3(64), dim3(256), 0, stream, hf, hb, Wout, bout, feats);
  hipLaunchKernelGGL(k_vit_chunkmat, dim3(NC), dim3(192), 0, stream, feats, trans, pmat);
  hipLaunchKernelGGL(k_vit_scan, dim3(1), dim3(192), 0, stream, pmat, trans, fvin, out, best);
  hipLaunchKernelGGL(k_vit_replay, dim3(NC), dim3(64), 0, stream, feats, trans, fvin, bptr);
  hipLaunchKernelGGL(k_bt_chunk, dim3(NC), dim3(64), 0, stream, bptr, cmap);
  hipLaunchKernelGGL(k_bt_scan, dim3(1), dim3(256), 0, stream, cmap, best, evec);
  hipLaunchKernelGGL(k_bt_replay, dim3(NC), dim3(64), 0, stream, bptr, evec, out);
}

// Round 3
// 15084.918 us; speedup vs baseline: 1.1444x; 1.1319x over previous
//
#include <hip/hip_runtime.h>
#include <cstdint>
#include <cstddef>

// ---------------- problem constants ----------------
namespace {
constexpr int Bb = 8, Ss = 2048, Ee = 256, Hh = 256, G4 = 1024, Tt = 12;
constexpr int NTOK = Bb * Ss;              // 16384 rows
constexpr int NC = 256, LCH = 64;          // viterbi chunking: 256 chunks x 64 steps
constexpr float FNEG = -10000.0f;
constexpr int START_TAG = 10, STOP_TAG = 11;

// ---------------- workspace layout (bytes) ----------------
constexpr size_t OFF_XS    = 0;                         // [16384][256] f32 gathered embeddings
constexpr size_t SZ_XS     = (size_t)NTOK * Ee * 4;
constexpr size_t OFF_WT    = OFF_XS + SZ_XS;            // [2][256][1024] f32 w_ih transposed
constexpr size_t SZ_WT     = (size_t)2 * Ee * G4 * 4;
constexpr size_t OFF_XPF   = OFF_WT + SZ_WT;            // [2048][8][1024] f32 x-proj fwd (bias folded)
constexpr size_t SZ_XP     = (size_t)Ss * Bb * G4 * 4;
constexpr size_t OFF_XPB   = OFF_XPF + SZ_XP;
constexpr size_t OFF_HF    = OFF_XPB + SZ_XP;           // [2048][8][256] f32 fwd hidden history
constexpr size_t SZ_H      = (size_t)Ss * Bb * Hh * 4;
constexpr size_t OFF_HB    = OFF_HF + SZ_H;
constexpr size_t OFF_FEATS = OFF_HB + SZ_H;             // [16384][12] f32
constexpr size_t SZ_FEATS  = (size_t)NTOK * Tt * 4;
constexpr size_t OFF_PMAT  = OFF_FEATS + SZ_FEATS;      // [256][144] f32 chunk max-plus mats
constexpr size_t SZ_PMAT   = (size_t)NC * 144 * 4;
constexpr size_t OFF_FVIN  = OFF_PMAT + SZ_PMAT;        // [256][12] f32 chunk-entry fv
constexpr size_t SZ_FVIN   = (size_t)NC * Tt * 4;
constexpr size_t OFF_BPTR  = OFF_FVIN + SZ_FVIN;        // [16384] u64 packed 12x4bit backptrs
constexpr size_t SZ_BPTR   = (size_t)NTOK * 8;
constexpr size_t OFF_CMAP  = OFF_BPTR + SZ_BPTR;        // [256][12] int chunk composed maps
constexpr size_t SZ_CMAP   = (size_t)NC * Tt * 4;
constexpr size_t OFF_EVEC  = OFF_CMAP + SZ_CMAP;        // [256] int tag at chunk-end
constexpr size_t SZ_EVEC   = (size_t)NC * 4;
constexpr size_t OFF_BEST  = OFF_EVEC + SZ_EVEC;        // [1] int
constexpr size_t SZ_BEST   = 256;
constexpr size_t OFF_HPK   = OFF_BEST + SZ_BEST;        // [2 dir][2048] u64 tagged h words
constexpr size_t SZ_HPK    = (size_t)2 * 2048 * 8;
constexpr size_t WS_NEED   = OFF_HPK + SZ_HPK;          // ~179 MB

__device__ __forceinline__ float4 f4fma(float a, float4 b, float4 c) {
  c.x = fmaf(a, b.x, c.x); c.y = fmaf(a, b.y, c.y);
  c.z = fmaf(a, b.z, c.z); c.w = fmaf(a, b.w, c.w);
  return c;
}
}  // namespace

// ---------------- gather embeddings: xs[r=t*8+b][k] = emb[sentence[b][t]][k] ----------------
__global__ __launch_bounds__(256) void k_gather(const int* __restrict__ sent,
                                                const float* __restrict__ emb,
                                                float* __restrict__ xs) {
  int rr = threadIdx.x >> 3, p = threadIdx.x & 7;
  int r = blockIdx.x * 32 + rr;
  int tg = r >> 3, bg = r & 7;
  int tok = sent[bg * Ss + tg];
  const float4* src = (const float4*)(emb + (size_t)tok * Ee) + p * 8;
  float4* dst = (float4*)(xs + (size_t)r * Ee) + p * 8;
#pragma unroll
  for (int i = 0; i < 8; ++i) dst[i] = src[i];
}

// ---------------- transpose w_ih -> wT[d][k][n] ----------------
__global__ __launch_bounds__(256) void k_transpose(const float* __restrict__ w_f,
                                                   const float* __restrict__ w_b,
                                                   float* __restrict__ wT) {
  int idx = blockIdx.x * 256 + threadIdx.x;
  if (idx >= 2 * Ee * G4) return;
  int d = idx >> 18;
  int rem = idx & 262143;
  int k = rem >> 10, n = rem & 1023;
  const float* w = d ? w_b : w_f;
  wT[idx] = w[n * Ee + k];
}

// ---------------- input projection GEMM: xp[r][n] = xs[r][:] . w_ih[n][:] + bias[n] ----------------
__global__ __launch_bounds__(256) void k_inproj(const float* __restrict__ xs,
                                                const float* __restrict__ wT,
                                                const float* __restrict__ b_f,
                                                const float* __restrict__ b_b,
                                                float* __restrict__ xpf,
                                                float* __restrict__ xpb) {
  const int dir = blockIdx.z;
  const float* wTd = wT + (size_t)dir * (Ee * G4);
  const float* bv = dir ? b_b : b_f;
  float* xp = dir ? xpb : xpf;
  const int rg = threadIdx.x >> 5, cg = threadIdx.x & 31;
  const int rbase = blockIdx.x * 32 + rg * 4;
  const int c0 = blockIdx.y * 128 + cg * 4;
  const float4* ap0 = (const float4*)(xs + (size_t)(rbase + 0) * Ee);
  const float4* ap1 = (const float4*)(xs + (size_t)(rbase + 1) * Ee);
  const float4* ap2 = (const float4*)(xs + (size_t)(rbase + 2) * Ee);
  const float4* ap3 = (const float4*)(xs + (size_t)(rbase + 3) * Ee);
  float4 acc0 = {0,0,0,0}, acc1 = {0,0,0,0}, acc2 = {0,0,0,0}, acc3 = {0,0,0,0};
#pragma unroll 4
  for (int k4 = 0; k4 < 64; ++k4) {
    float4 a0 = ap0[k4], a1 = ap1[k4], a2 = ap2[k4], a3 = ap3[k4];
    const float* wb = wTd + (size_t)(k4 * 4) * G4 + c0;
    float4 b0 = *(const float4*)(wb);
    float4 b1 = *(const float4*)(wb + G4);
    float4 b2 = *(const float4*)(wb + 2 * G4);
    float4 b3 = *(const float4*)(wb + 3 * G4);
    acc0 = f4fma(a0.x, b0, acc0); acc0 = f4fma(a0.y, b1, acc0);
    acc0 = f4fma(a0.z, b2, acc0); acc0 = f4fma(a0.w, b3, acc0);
    acc1 = f4fma(a1.x, b0, acc1); acc1 = f4fma(a1.y, b1, acc1);
    acc1 = f4fma(a1.z, b2, acc1); acc1 = f4fma(a1.w, b3, acc1);
    acc2 = f4fma(a2.x, b0, acc2); acc2 = f4fma(a2.y, b1, acc2);
    acc2 = f4fma(a2.z, b2, acc2); acc2 = f4fma(a2.w, b3, acc2);
    acc3 = f4fma(a3.x, b0, acc3); acc3 = f4fma(a3.y, b1, acc3);
    acc3 = f4fma(a3.z, b2, acc3); acc3 = f4fma(a3.w, b3, acc3);
  }
  float4 bias = *(const float4*)(bv + c0);
  acc0.x += bias.x; acc0.y += bias.y; acc0.z += bias.z; acc0.w += bias.w;
  acc1.x += bias.x; acc1.y += bias.y; acc1.z += bias.z; acc1.w += bias.w;
  acc2.x += bias.x; acc2.y += bias.y; acc2.z += bias.z; acc2.w += bias.w;
  acc3.x += bias.x; acc3.y += bias.y; acc3.z += bias.z; acc3.w += bias.w;
  *(float4*)(xp + (size_t)(rbase + 0) * G4 + c0) = acc0;
  *(float4*)(xp + (size_t)(rbase + 1) * G4 + c0) = acc1;
  *(float4*)(xp + (size_t)(rbase + 2) * G4 + c0) = acc2;
  *(float4*)(xp + (size_t)(rbase + 3) * G4 + c0) = acc3;
}

// ---------------- persistent bidirectional LSTM recurrence ----------------
// 16 blocks: wg 0..7 forward, 8..15 backward. Each WG owns 32 hidden channels
// (=128 gate rows), w_hh slice in VGPRs. Per-step all-to-all h exchange via
// tagged u64 words, accessed EXCLUSIVELY with agent-scope RMW atomics:
// writer = atomic exchange, reader = atomic fetch_add(0). RMWs execute at the
// device coherence point (MALL) -- never satisfied by the non-coherent
// per-XCD L2 (plain loads/stores were: R2 showed stale-L2 spin ~7us/step).
__global__ __launch_bounds__(512, 2) void k_lstm(
    const float* __restrict__ whh_f, const float* __restrict__ whh_b,
    const float* __restrict__ h0, const float* __restrict__ c0,
    const float* __restrict__ xpf, const float* __restrict__ xpb,
    float* __restrict__ hist_f, float* __restrict__ hist_b,
    unsigned long long* hpack) {
  __shared__ __align__(16) float h_lds[2048];   // [j][b]
  __shared__ float part[128 * 33];              // [row][ks*8 + b], pad 33

  const int wg = blockIdx.x, dir = wg >> 3, j0 = (wg & 7) * 32;
  const int t = threadIdx.x;
  const float* whh = dir ? whh_b : whh_f;
  const float* xp = dir ? xpb : xpf;
  float* hist = dir ? hist_b : hist_f;
  unsigned long long* hpk = hpack + dir * 2048;

  // FMA-thread mapping: rowg in lanes, (ks,bs) wave-uniform
  const int rowg = t & 63, ks = (t >> 6) & 3, bs = t >> 8;
  const int row0 = rowg * 2, row1 = rowg * 2 + 1;
  const int n0 = ((row0 >> 5) << 8) + j0 + (row0 & 31);
  const int n1 = ((row1 >> 5) << 8) + j0 + (row1 & 31);
  float4 w0r[16], w1r[16];
  {
    const float4* p0 = (const float4*)(whh + (size_t)n0 * Hh + ks * 64);
    const float4* p1 = (const float4*)(whh + (size_t)n1 * Hh + ks * 64);
#pragma unroll
    for (int q = 0; q < 16; ++q) { w0r[q] = p0[q]; w1r[q] = p1[q]; }
  }
  // gate-thread mapping (t<256): owns hidden unit (j0+jj, batch bg)
  const int jj = t >> 3, bg = t & 7;
  float c_reg = 0.0f;
  if (t < 256) c_reg = c0[dir * 2048 + bg * Hh + j0 + jj];

  for (int s = 0; s < Ss; ++s) {
    const int tg = dir ? (Ss - 1 - s) : s;
    // gate threads prefetch their 4 x-proj values (used after barrier 2)
    float xq0 = 0.f, xq1 = 0.f, xq2 = 0.f, xq3 = 0.f;
    if (t < 256) {
      const float* xpt = xp + (size_t)tg * 8192 + bg * G4 + j0 + jj;
      xq0 = xpt[0]; xq1 = xpt[256]; xq2 = xpt[512]; xq3 = xpt[768];
    }
    // fill h_lds[j][b] with h_{s-1}
    if (s == 0) {
#pragma unroll
      for (int i = 0; i < 4; ++i) {
        int idx = t * 4 + i;
        h_lds[idx] = h0[dir * 2048 + (idx & 7) * Hh + (idx >> 3)];
      }
    } else {
      const unsigned long long tagv = (unsigned long long)s;
      unsigned long long* p = hpk + 4 * t;
      unsigned long long w0, w1, w2, w3;
      for (;;) {
        w0 = __hip_atomic_fetch_add(p + 0, 0ULL, __ATOMIC_RELAXED, __HIP_MEMORY_SCOPE_AGENT);
        w1 = __hip_atomic_fetch_add(p + 1, 0ULL, __ATOMIC_RELAXED, __HIP_MEMORY_SCOPE_AGENT);
        w2 = __hip_atomic_fetch_add(p + 2, 0ULL, __ATOMIC_RELAXED, __HIP_MEMORY_SCOPE_AGENT);
        w3 = __hip_atomic_fetch_add(p + 3, 0ULL, __ATOMIC_RELAXED, __HIP_MEMORY_SCOPE_AGENT);
        if (((w0 >> 32) == tagv) & ((w1 >> 32) == tagv) &
            ((w2 >> 32) == tagv) & ((w3 >> 32) == tagv)) break;
        __builtin_amdgcn_s_sleep(1);
      }
      float4 hv4;
      hv4.x = __uint_as_float((unsigned)w0);
      hv4.y = __uint_as_float((unsigned)w1);
      hv4.z = __uint_as_float((unsigned)w2);
      hv4.w = __uint_as_float((unsigned)w3);
      ((float4*)h_lds)[t] = hv4;
    }
    __syncthreads();  // B1: h_lds ready, prev-step gates done (part[] reusable)
    // recurrent GEMM partials: 2 rows x 64 k x 4 b per thread
    float4 accA = {0,0,0,0}, accB = {0,0,0,0};
    const float4* hrow = ((const float4*)h_lds) + ks * 128 + bs;
#pragma unroll
    for (int q = 0; q < 16; ++q) {
      float4 wa = w0r[q], wb = w1r[q];
      float4 hx = hrow[(q * 4 + 0) * 2];
      float4 hy = hrow[(q * 4 + 1) * 2];
      float4 hz = hrow[(q * 4 + 2) * 2];
      float4 hw = hrow[(q * 4 + 3) * 2];
      accA = f4fma(wa.x, hx, accA); accA = f4fma(wa.y, hy, accA);
      accA = f4fma(wa.z, hz, accA); accA = f4fma(wa.w, hw, accA);
      accB = f4fma(wb.x, hx, accB); accB = f4fma(wb.y, hy, accB);
      accB = f4fma(wb.z, hz, accB); accB = f4fma(wb.w, hw, accB);
    }
    {
      int pa = row0 * 33 + ks * 8 + bs * 4;
      part[pa + 0] = accA.x; part[pa + 1] = accA.y;
      part[pa + 2] = accA.z; part[pa + 3] = accA.w;
      int pb = row1 * 33 + ks * 8 + bs * 4;
      part[pb + 0] = accB.x; part[pb + 1] = accB.y;
      part[pb + 2] = accB.z; part[pb + 3] = accB.w;
    }
    __syncthreads();  // B2: part[] complete
    // fused ks-reduce + gates (PyTorch order i,f,g,o) + publish + hist
    if (t < 256) {
      float z0 = xq0, z1 = xq1, z2 = xq2, z3 = xq3;
#pragma unroll
      for (int kq = 0; kq < 4; ++kq) {
        z0 += part[(jj) * 33 + kq * 8 + bg];
        z1 += part[(32 + jj) * 33 + kq * 8 + bg];
        z2 += part[(64 + jj) * 33 + kq * 8 + bg];
        z3 += part[(96 + jj) * 33 + kq * 8 + bg];
      }
      float iv = 1.0f / (1.0f + expf(-z0));
      float fv = 1.0f / (1.0f + expf(-z1));
      float gv = tanhf(z2);
      float ov = 1.0f / (1.0f + expf(-z3));
      c_reg = fv * c_reg + iv * gv;
      float hv = ov * tanhf(c_reg);
      // publish FIRST (critical path for all peer WGs): RMW at coherence point
      unsigned long long wv =
          ((unsigned long long)(unsigned)(s + 1) << 32) |
          (unsigned long long)__float_as_uint(hv);
      (void)__hip_atomic_exchange(hpk + (size_t)(j0 + jj) * 8 + bg, wv,
                                  __ATOMIC_RELAXED, __HIP_MEMORY_SCOPE_AGENT);
      hist[(size_t)tg * 2048 + bg * Hh + j0 + jj] = hv;
    }
    // no barrier here: next-iteration B1 orders part[] reuse
  }
}

// ---------------- feats = [hf|hb] @ W_out^T + b_out ----------------
__global__ __launch_bounds__(256) void k_feats(const float* __restrict__ hist_f,
                                               const float* __restrict__ hist_b,
                                               const float* __restrict__ Wout,
                                               const float* __restrict__ bout,
                                               float* __restrict__ feats) {
  __shared__ float wsh[Tt * 512];
  __shared__ float bsh[Tt];
  for (int i = threadIdx.x; i < Tt * 512; i += 256) wsh[i] = Wout[i];
  if (threadIdx.x < Tt) bsh[threadIdx.x] = bout[threadIdx.x];
  __syncthreads();
  int r = blockIdx.x * 256 + threadIdx.x;
  int bq = r >> 11, sq = r & 2047;
  const float4* hf4 = (const float4*)(hist_f + (size_t)sq * 2048 + bq * Hh);
  const float4* hb4 = (const float4*)(hist_b + (size_t)sq * 2048 + bq * Hh);
  float acc[Tt];
#pragma unroll
  for (int j = 0; j < Tt; ++j) acc[j] = bsh[j];
  for (int k4 = 0; k4 < 64; ++k4) {
    float4 x = hf4[k4];
#pragma unroll
    for (int j = 0; j < Tt; ++j) {
      float4 w = *(const float4*)&wsh[j * 512 + k4 * 4];
      acc[j] = fmaf(x.x, w.x, fmaf(x.y, w.y, fmaf(x.z, w.z, fmaf(x.w, w.w, acc[j]))));
    }
  }
  for (int k4 = 0; k4 < 64; ++k4) {
    float4 x = hb4[k4];
#pragma unroll
    for (int j = 0; j < Tt; ++j) {
      float4 w = *(const float4*)&wsh[j * 512 + 256 + k4 * 4];
      acc[j] = fmaf(x.x, w.x, fmaf(x.y, w.y, fmaf(x.z, w.z, fmaf(x.w, w.w, acc[j]))));
    }
  }
#pragma unroll
  for (int j = 0; j < Tt; ++j) feats[(size_t)r * Tt + j] = acc[j];
}

// ---------------- Viterbi phase 1: per-chunk max-plus matrix product ----------------
__global__ __launch_bounds__(192) void k_vit_chunkmat(const float* __restrict__ feats,
                                                      const float* __restrict__ trans,
                                                      float* __restrict__ pmat) {
  __shared__ float R[2][144];
  __shared__ float fe[LCH * Tt];
  __shared__ float ts[144];
  const int t = threadIdx.x, c = blockIdx.x;
  for (int i = t; i < LCH * Tt; i += 192) fe[i] = feats[(size_t)c * LCH * Tt + i];
  if (t < 144) ts[t] = trans[t];
  __syncthreads();
  int j = 0, k = 0;
  float trow[12];
  if (t < 144) {
    j = t / 12; k = t - j * 12;
#pragma unroll
    for (int m = 0; m < 12; ++m) trow[m] = ts[j * 12 + m];
    R[0][t] = ts[t] + fe[j];  // A_{t0}
  }
  __syncthreads();
  for (int i = 1; i < LCH; ++i) {
    int p = (i - 1) & 1;
    if (t < 144) {
      float m = trow[0] + R[p][k];
#pragma unroll
      for (int mm = 1; mm < 12; ++mm) m = fmaxf(m, trow[mm] + R[p][mm * 12 + k]);
      R[p ^ 1][t] = m + fe[i * 12 + j];
    }
    __syncthreads();
  }
  if (t < 144) pmat[(size_t)c * 144 + t] = R[(LCH - 1) & 1][t];
}

// ---------------- Viterbi phase 2: sequential scan over chunk matrices ----------------
__global__ __launch_bounds__(192) void k_vit_scan(const float* __restrict__ pmat,
                                                  const float* __restrict__ trans,
                                                  float* __restrict__ fvin,
                                                  float* __restrict__ dout,
                                                  int* __restrict__ best) {
  __shared__ float fv[12];
  __shared__ float sl[144];
  __shared__ float term[12];
  const int t = threadIdx.x;
  const int j = t / 12, k = t - j * 12;
  if (t < 12) fv[t] = (t == START_TAG) ? 0.0f : FNEG;
  float pv = (t < 144) ? pmat[t] : 0.0f;
  __syncthreads();
  for (int c = 0; c < NC; ++c) {
    if (t < 12) fvin[c * 12 + t] = fv[t];
    float pnext = (t < 144 && c + 1 < NC) ? pmat[(size_t)(c + 1) * 144 + t] : 0.0f;
    if (t < 144) sl[t] = pv + fv[k];
    __syncthreads();
    if (t < 12) {
      float m = sl[t * 12];
#pragma unroll
      for (int kk = 1; kk < 12; ++kk) m = fmaxf(m, sl[t * 12 + kk]);
      fv[t] = m;
    }
    __syncthreads();
    pv = pnext;
  }
  if (t < 12) term[t] = fv[t] + trans[STOP_TAG * 12 + t];
  __syncthreads();
  if (t == 0) {
    float m = term[0]; int a = 0;
    for (int q = 1; q < 12; ++q) { if (term[q] > m) { m = term[q]; a = q; } }
    dout[0] = m;
    best[0] = a;
  }
}

// ---------------- Viterbi phase 3: replay chunks -> packed backpointers ----------------
__global__ __launch_bounds__(64) void k_vit_replay(const float* __restrict__ feats,
                                                   const float* __restrict__ trans,
                                                   const float* __restrict__ fvin,
                                                   unsigned long long* __restrict__ bptr) {
  __shared__ float fe[LCH * Tt];
  __shared__ float fv[12];
  __shared__ int bpn[12];
  const int t = threadIdx.x, c = blockIdx.x;
  for (int i = t; i < LCH * Tt; i += 64) fe[i] = feats[(size_t)c * LCH * Tt + i];
  float trow[12];
  if (t < 12) {
#pragma unroll
    for (int m = 0; m < 12; ++m) trow[m] = trans[t * 12 + m];
    fv[t] = fvin[c * 12 + t];
  }
  __syncthreads();
  for (int i = 0; i < LCH; ++i) {
    float nm = 0.0f;
    if (t < 12) {
      float m = fv[0] + trow[0]; int a = 0;
#pragma unroll
      for (int k = 1; k < 12; ++k) {
        float v = fv[k] + trow[k];
        if (v > m) { m = v; a = k; }   // first-max wins, matches jnp.argmax
      }
      nm = m + fe[i * 12 + t];
      bpn[t] = a;
    }
    __syncthreads();
    if (t < 12) fv[t] = nm;
    if (t == 0) {
      unsigned long long bp = 0;
#pragma unroll
      for (int jq = 0; jq < 12; ++jq)
        bp |= (unsigned long long)(unsigned)bpn[jq] << (4 * jq);
      bptr[(size_t)c * LCH + i] = bp;
    }
    __syncthreads();
  }
}

// ---------------- backtrace phase A: compose per-chunk tag maps ----------------
__global__ __launch_bounds__(64) void k_bt_chunk(const unsigned long long* __restrict__ bptr,
                                                 int* __restrict__ cmap) {
  __shared__ unsigned long long bp[LCH];
  const int t = threadIdx.x, c = blockIdx.x;
  if (t < LCH) bp[t] = bptr[(size_t)c * LCH + t];
  __syncthreads();
  if (t < 12) {
    int v = t;
    for (int i = LCH - 1; i >= 0; --i) v = (int)((bp[i] >> (4 * v)) & 15ULL);
    cmap[c * 12 + t] = v;
  }
}

// ---------------- backtrace phase B: scan chunk maps ----------------
__global__ __launch_bounds__(256) void k_bt_scan(const int* __restrict__ cmap,
                                                 const int* __restrict__ best,
                                                 int* __restrict__ evec) {
  __shared__ int cm[NC * 12];
  __shared__ int es[NC];
  const int t = threadIdx.x;
  for (int i = t; i < NC * 12; i += 256) cm[i] = cmap[i];
  __syncthreads();
  if (t == 0) {
    int tag = best[0];
    es[NC - 1] = tag;
    for (int c = NC - 1; c >= 1; --c) { tag = cm[c * 12 + tag]; es[c - 1] = tag; }
  }
  __syncthreads();
  evec[t] = es[t];
}

// ---------------- backtrace phase C: emit path ----------------
__global__ __launch_bounds__(64) void k_bt_replay(const unsigned long long* __restrict__ bptr,
                                                  const int* __restrict__ evec,
                                                  float* __restrict__ dout) {
  __shared__ unsigned long long bp[LCH];
  __shared__ int tgs[LCH];
  const int t = threadIdx.x, c = blockIdx.x;
  if (t < LCH) bp[t] = bptr[(size_t)c * LCH + t];
  __syncthreads();
  if (t == 0) {
    int tag = evec[c];  // tag at global index (c+1)*LCH
    for (int i = LCH - 1; i >= 0; --i) {
      tgs[i] = tag;                              // out[c*LCH+i] = tag_{c*LCH+i+1}
      tag = (int)((bp[i] >> (4 * tag)) & 15ULL);
    }
  }
  __syncthreads();
  dout[1 + c * LCH + t] = (float)tgs[t];
}

// ---------------- launcher ----------------
extern "C" void kernel_launch(void* const* d_in, const int* in_sizes, int n_in,
                              void* d_out, int out_size, void* d_ws, size_t ws_size,
                              hipStream_t stream) {
  const int*   sent = (const int*)d_in[0];
  const float* emb  = (const float*)d_in[1];
  const float* wihf = (const float*)d_in[2];
  const float* whhf = (const float*)d_in[3];
  const float* bf   = (const float*)d_in[4];
  const float* wihb = (const float*)d_in[5];
  const float* whhb = (const float*)d_in[6];
  const float* bb   = (const float*)d_in[7];
  const float* h0   = (const float*)d_in[8];
  const float* c0   = (const float*)d_in[9];
  const float* Wout = (const float*)d_in[10];
  const float* bout = (const float*)d_in[11];
  const float* trans= (const float*)d_in[12];
  float* out = (float*)d_out;
  char* ws = (char*)d_ws;
  if (ws_size < WS_NEED) return;  // workspace too small: bail (visible as wrong output)

  float* xs    = (float*)(ws + OFF_XS);
  float* wT    = (float*)(ws + OFF_WT);
  float* xpf   = (float*)(ws + OFF_XPF);
  float* xpb   = (float*)(ws + OFF_XPB);
  float* hf    = (float*)(ws + OFF_HF);
  float* hb    = (float*)(ws + OFF_HB);
  float* feats = (float*)(ws + OFF_FEATS);
  float* pmat  = (float*)(ws + OFF_PMAT);
  float* fvin  = (float*)(ws + OFF_FVIN);
  unsigned long long* bptr = (unsigned long long*)(ws + OFF_BPTR);
  int*   cmap  = (int*)(ws + OFF_CMAP);
  int*   evec  = (int*)(ws + OFF_EVEC);
  int*   best  = (int*)(ws + OFF_BEST);
  unsigned long long* hpack = (unsigned long long*)(ws + OFF_HPK);

  hipLaunchKernelGGL(k_gather, dim3(512), dim3(256), 0, stream, sent, emb, xs);
  hipLaunchKernelGGL(k_transpose, dim3(2048), dim3(256), 0, stream, wihf, wihb, wT);
  hipLaunchKernelGGL(k_inproj, dim3(512, 8, 2), dim3(256), 0, stream,
                     xs, wT, bf, bb, xpf, xpb);
  hipLaunchKernelGGL(k_lstm, dim3(16), dim3(512), 0, stream,
                     whhf, whhb, h0, c0, xpf, xpb, hf, hb, hpack);
  hipLaunchKernelGGL(k_feats, dim3(64), dim3(256), 0, stream, hf, hb, Wout, bout, feats);
  hipLaunchKernelGGL(k_vit_chunkmat, dim3(NC), dim3(192), 0, stream, feats, trans, pmat);
  hipLaunchKernelGGL(k_vit_scan, dim3(1), dim3(192), 0, stream, pmat, trans, fvin, out, best);
  hipLaunchKernelGGL(k_vit_replay, dim3(NC), dim3(64), 0, stream, feats, trans, fvin, bptr);
  hipLaunchKernelGGL(k_bt_chunk, dim3(NC), dim3(64), 0, stream, bptr, cmap);
  hipLaunchKernelGGL(k_bt_scan, dim3(1), dim3(256), 0, stream, cmap, best, evec);
  hipLaunchKernelGGL(k_bt_replay, dim3(NC), dim3(64), 0, stream, bptr, evec, out);
}